// Round 10
// baseline (988.867 us; speedup 1.0000x reference)
//
#include <hip/hip_runtime.h>
#include <hip/hip_bf16.h>
#include <math.h>

#define S_LEN 2048
#define HID   2048

typedef __bf16 bf16x8 __attribute__((ext_vector_type(8)));
typedef float  f32x4  __attribute__((ext_vector_type(4)));

__device__ __forceinline__ unsigned short f2b(float x) {
  __hip_bfloat16 h = __float2bfloat16(x);
  return __builtin_bit_cast(unsigned short, h);
}

__device__ __forceinline__ float block_sum_256(float v) {
  __shared__ float red[4];
  #pragma unroll
  for (int o = 32; o > 0; o >>= 1) v += __shfl_down(v, o, 64);
  if ((threadIdx.x & 63) == 0) red[threadIdx.x >> 6] = v;
  __syncthreads();
  v = red[0] + red[1] + red[2] + red[3];
  __syncthreads();
  return v;
}

// ---------------- embedding ----------------
__global__ __launch_bounds__(256) void embed_kernel(
    const int* __restrict__ ids, const float* __restrict__ vemb,
    const float* __restrict__ aemb, float* __restrict__ h, int* __restrict__ amask) {
  const int s = blockIdx.x;
  const int id = ids[s];
  const bool am = id > 31999;
  if (threadIdx.x == 0) amask[s] = am ? 1 : 0;
  const int d0 = threadIdx.x * 8;
  float out[8];
  if (am) {
    const int at = id - 32000;
    #pragma unroll
    for (int u = 0; u < 8; u++) out[u] = 0.f;
    for (int cb = 0; cb < 8; cb++) {
      const float* src = aemb + (long)(at + cb * 1024) * HID + d0;
      #pragma unroll
      for (int u = 0; u < 8; u++) out[u] += src[u];
    }
  } else {
    const float* src = vemb + (long)id * HID + d0;
    #pragma unroll
    for (int u = 0; u < 8; u++) out[u] = src[u];
  }
  float* dst = h + (long)s * HID + d0;
  #pragma unroll
  for (int u = 0; u < 8; u++) dst[u] = out[u];
}

// ---------------- row partition ----------------
__global__ __launch_bounds__(256) void partition_rows(
    const int* __restrict__ ids, int* __restrict__ apos, int* __restrict__ cnt) {
  __shared__ int ca[256];
  __shared__ int sc[257];
  const int t = threadIdx.x;
  int m[8], loc = 0;
  #pragma unroll
  for (int i = 0; i < 8; i++) { m[i] = ids[t * 8 + i] > 31999 ? 1 : 0; loc += m[i]; }
  ca[t] = loc;
  __syncthreads();
  if (t == 0) {
    int run = 0;
    for (int i = 0; i < 256; i++) { sc[i] = run; run += ca[i]; }
    sc[256] = run;
  }
  __syncthreads();
  int off = sc[t];
  #pragma unroll
  for (int i = 0; i < 8; i++) {
    const int s = t * 8 + i;
    if (m[i]) { apos[s] = off; off++; }
    else apos[s] = -1;
  }
  if (t == 0) { cnt[0] = sc[256]; cnt[1] = (sc[256] + 127) & ~127; }
}

__global__ void init_ctrs(int* c) { c[threadIdx.x] = 0; }

__global__ __launch_bounds__(256) void init_stats(float* __restrict__ stm, float* __restrict__ stl) {
  const int i = blockIdx.x * 256 + threadIdx.x;  // 65536 = 2*16*2048
  stm[i] = -1e30f;
  stl[i] = 0.f;
}

// ---------------- weight transpose + f32->bf16 (64x64 tile, float4) ----------------
__global__ __launch_bounds__(256) void transposew(
    const float* __restrict__ W, int ldw, unsigned short* __restrict__ Wt, int K, int N) {
  __shared__ float t[64][65];
  const int k0 = blockIdx.y * 64, n0 = blockIdx.x * 64;
  const int q = threadIdx.x & 15;
  const int r0 = threadIdx.x >> 4;
  #pragma unroll
  for (int i = 0; i < 4; i++) {
    const int row = r0 + i * 16;
    const float4 v = *(const float4*)(W + (long)(k0 + row) * ldw + n0 + q * 4);
    t[row][q * 4 + 0] = v.x; t[row][q * 4 + 1] = v.y;
    t[row][q * 4 + 2] = v.z; t[row][q * 4 + 3] = v.w;
  }
  __syncthreads();
  #pragma unroll
  for (int i = 0; i < 4; i++) {
    const int n = r0 + i * 16;
    ushort4 o;
    o.x = f2b(t[q * 4 + 0][n]); o.y = f2b(t[q * 4 + 1][n]);
    o.z = f2b(t[q * 4 + 2][n]); o.w = f2b(t[q * 4 + 3][n]);
    *(ushort4*)(Wt + (long)(n0 + n) * K + k0 + q * 4) = o;
  }
}

// bf16 transpose: V [2048][512] -> Vt [512][2048]
__global__ __launch_bounds__(256) void transpose_b16(
    const unsigned short* __restrict__ V, unsigned short* __restrict__ Vt) {
  __shared__ unsigned short t[64][72];
  const int s0 = blockIdx.y * 64, d0 = blockIdx.x * 64;
  const int q = threadIdx.x & 15;
  const int r0 = threadIdx.x >> 4;
  #pragma unroll
  for (int i = 0; i < 4; i++) {
    const int row = r0 + i * 16;
    const ushort4 v = *(const ushort4*)(V + (long)(s0 + row) * 512 + d0 + q * 4);
    t[row][q * 4 + 0] = v.x; t[row][q * 4 + 1] = v.y;
    t[row][q * 4 + 2] = v.z; t[row][q * 4 + 3] = v.w;
  }
  __syncthreads();
  #pragma unroll
  for (int i = 0; i < 4; i++) {
    const int d = r0 + i * 16;
    ushort4 o;
    o.x = t[q * 4 + 0][d]; o.y = t[q * 4 + 1][d];
    o.z = t[q * 4 + 2][d]; o.w = t[q * 4 + 3][d];
    *(ushort4*)(Vt + (long)(d0 + d) * 2048 + s0 + q * 4) = o;
  }
}

// ---------------- RoPE table ----------------
__global__ __launch_bounds__(256) void rope_table(float* __restrict__ c, float* __restrict__ s_) {
  const int i = blockIdx.x * 256 + threadIdx.x;
  const int pos = i >> 6, j = i & 63;
  const float inv = powf(10000.f, -(float)(2 * j) * (1.f / 128.f));
  const float ang = (float)pos * inv;
  c[i] = cosf(ang);
  s_[i] = sinf(ang);
}

// ---------------- RMSNorms ----------------
__global__ __launch_bounds__(256) void rmsnorm_sel(
    const float* __restrict__ x, const int* __restrict__ amask,
    const float* __restrict__ wt, const float* __restrict__ wa, unsigned short* __restrict__ out) {
  const long s = blockIdx.x;
  const float* xr = x + s * HID;
  const int d0 = threadIdx.x * 8;
  float v[8], ss = 0.f;
  #pragma unroll
  for (int u = 0; u < 8; u++) { v[u] = xr[d0 + u]; ss += v[u] * v[u]; }
  ss = block_sum_256(ss) * (1.f / HID);
  const float rr = rsqrtf(ss + 1e-5f);
  const float* w = amask[s] ? wa : wt;
  #pragma unroll
  for (int u = 0; u < 8; u++) out[s * HID + d0 + u] = f2b(v[u] * rr * w[d0 + u]);
}

__global__ __launch_bounds__(256) void rmsnorm_post(
    const float* __restrict__ x, const int* __restrict__ apos,
    const float* __restrict__ wt, const float* __restrict__ wa,
    unsigned short* __restrict__ hnt, unsigned short* __restrict__ hna_g) {
  const long s = blockIdx.x;
  const float* xr = x + s * HID;
  const int d0 = threadIdx.x * 8;
  float v[8], ss = 0.f;
  #pragma unroll
  for (int u = 0; u < 8; u++) { v[u] = xr[d0 + u]; ss += v[u] * v[u]; }
  ss = block_sum_256(ss) * (1.f / HID);
  const float rr = rsqrtf(ss + 1e-5f);
  const int ap = apos[s];
  #pragma unroll
  for (int u = 0; u < 8; u++) {
    const float xn = v[u] * rr;
    hnt[s * HID + d0 + u] = f2b(xn * wt[d0 + u]);
    if (ap >= 0) hna_g[(long)ap * HID + d0 + u] = f2b(xn * wa[d0 + u]);
  }
}

__global__ __launch_bounds__(256) void rmsnorm_final(
    const float* __restrict__ x, const float* __restrict__ w, float* __restrict__ out) {
  const long s = blockIdx.x;
  const float* xr = x + s * HID;
  const int d0 = threadIdx.x * 8;
  float v[8], ss = 0.f;
  #pragma unroll
  for (int u = 0; u < 8; u++) { v[u] = xr[d0 + u]; ss += v[u] * v[u]; }
  ss = block_sum_256(ss) * (1.f / HID);
  const float rr = rsqrtf(ss + 1e-5f);
  #pragma unroll
  for (int u = 0; u < 8; u++) out[s * HID + d0 + u] = v[u] * rr * w[d0 + u];
}

__device__ __forceinline__ void gload16(const void* g, void* l) {
  __builtin_amdgcn_global_load_lds((const __attribute__((address_space(1))) void*)g,
                                   (__attribute__((address_space(3))) void*)l, 16, 0, 0);
}

#define ABAR() do { __builtin_amdgcn_s_barrier(); \
  asm volatile("" ::: "memory"); __builtin_amdgcn_sched_barrier(0); } while (0)

// ---------------- single-pass flash attention (kv-chunked) ----------------
__global__ __launch_bounds__(512, 1) void attn_flash(
    const unsigned short* __restrict__ qb, const unsigned short* __restrict__ kb,
    const unsigned short* __restrict__ vt, float* __restrict__ opart,
    float* __restrict__ stm, float* __restrict__ stl,
    int* __restrict__ ctr, float iscale) {
  __shared__ __align__(16) unsigned short Kb[2][2][128][64];
  __shared__ __align__(16) unsigned short Vb[2][128][64];
  __shared__ __align__(16) unsigned short Pb[8][16][144];
  __shared__ int s_item;
  const int tid = threadIdx.x;
  const int lane = tid & 63;
  const int w = tid >> 6;
  const int lr = lane & 15;
  const int kg = lane >> 4;
  const int trow = tid >> 3;
  const int tc = tid & 7;

  for (;;) {
    if (tid == 0) s_item = atomicAdd(ctr, 1);
    __syncthreads();
    const int item = s_item;
    __syncthreads();
    if (item >= 512) break;
    const int qq = 15 - (item >> 5);
    const int h = item & 15;
    const int cch = (item >> 4) & 1;
    const int kvh = h >> 2;
    const int bm = qq * 128;
    const int nt = qq + 1;
    const int tmid = (nt + 1) >> 1;
    const int t0 = cch ? tmid : 0;
    const int t1 = cch ? nt : tmid;
    if (t0 >= t1) continue;

    bf16x8 af_q[4];
    {
      const unsigned short* qr = qb + (long)(bm + w * 16 + lr) * 2048 + h * 128 + kg * 8;
      #pragma unroll
      for (int c = 0; c < 4; c++) af_q[c] = *(const bf16x8*)(qr + c * 32);
    }
    float m[4], l[4];
    #pragma unroll
    for (int r = 0; r < 4; r++) { m[r] = -1e30f; l[r] = 0.f; }
    f32x4 acc_o[8];
    #pragma unroll
    for (int nf = 0; nf < 8; nf++) acc_o[nf] = (f32x4){0.f, 0.f, 0.f, 0.f};

    auto stageK = [&](int buf, int t) {
      const int kv0 = t * 128;
      #pragma unroll
      for (int hh2 = 0; hh2 < 2; hh2++)
        #pragma unroll
        for (int rr = 0; rr < 2; rr++) {
          const int row = trow + rr * 64;
          gload16(kb + (long)(kv0 + row) * 512 + kvh * 128 + hh2 * 64 + ((tc ^ (row & 7)) * 8),
                  &Kb[buf][hh2][row][tc * 8]);
        }
    };
    auto stageV = [&](int t) {
      const int kv0 = t * 128;
      #pragma unroll
      for (int hh2 = 0; hh2 < 2; hh2++)
        #pragma unroll
        for (int rr = 0; rr < 2; rr++) {
          const int row = trow + rr * 64;
          gload16(vt + (long)(kvh * 128 + row) * 2048 + kv0 + hh2 * 64 + ((tc ^ (row & 7)) * 8),
                  &Vb[hh2][row][tc * 8]);
        }
    };

    stageK(t0 & 1, t0);
    for (int t = t0; t < t1; t++) {
      const bool hn = (t + 1) < t1;
      stageV(t);
      if (hn) stageK((t + 1) & 1, t + 1);
      if (hn) { asm volatile("s_waitcnt vmcnt(8)" ::: "memory"); }
      else    { asm volatile("s_waitcnt vmcnt(4)" ::: "memory"); }
      ABAR();
      f32x4 acc[8];
      #pragma unroll
      for (int nf = 0; nf < 8; nf++) acc[nf] = (f32x4){0.f, 0.f, 0.f, 0.f};
      #pragma unroll
      for (int c = 0; c < 4; c++) {
        #pragma unroll
        for (int nf = 0; nf < 8; nf++) {
          const int row = nf * 16 + lr;
          bf16x8 bk = *(const bf16x8*)(&Kb[t & 1][c >> 1][row][(((c & 1) * 4 + kg) ^ (row & 7)) * 8]);
          acc[nf] = __builtin_amdgcn_mfma_f32_16x16x32_bf16(af_q[c], bk, acc[nf], 0, 0, 0);
        }
      }
      const bool diag = (t == nt - 1);
      #pragma unroll
      for (int r = 0; r < 4; r++) {
        const int rowg = bm + w * 16 + kg * 4 + r;
        float sv[8], tmax = -1e30f;
        #pragma unroll
        for (int nf = 0; nf < 8; nf++) {
          float s = acc[nf][r] * iscale;
          const int colg = t * 128 + nf * 16 + lr;
          if (diag && colg > rowg) s = -1e30f;
          sv[nf] = s;
          tmax = fmaxf(tmax, s);
        }
        #pragma unroll
        for (int o = 1; o < 16; o <<= 1) tmax = fmaxf(tmax, __shfl_xor(tmax, o, 64));
        const float mn = fmaxf(m[r], tmax);
        const float scal = __expf(m[r] - mn);
        float psum = 0.f;
        #pragma unroll
        for (int nf = 0; nf < 8; nf++) {
          const float pe = __expf(sv[nf] - mn);
          psum += pe;
          Pb[w][kg * 4 + r][nf * 16 + lr] = f2b(pe);
        }
        #pragma unroll
        for (int o = 1; o < 16; o <<= 1) psum += __shfl_xor(psum, o, 64);
        l[r] = l[r] * scal + psum;
        m[r] = mn;
        #pragma unroll
        for (int nf = 0; nf < 8; nf++) acc_o[nf][r] *= scal;
      }
      asm volatile("s_waitcnt lgkmcnt(0)" ::: "memory");
      __builtin_amdgcn_sched_barrier(0);
      if (hn) { asm volatile("s_waitcnt vmcnt(4)" ::: "memory"); }
      else    { asm volatile("s_waitcnt vmcnt(0)" ::: "memory"); }
      ABAR();
      #pragma unroll
      for (int c = 0; c < 4; c++) {
        bf16x8 ap = *(const bf16x8*)(&Pb[w][lr][c * 32 + kg * 8]);
        #pragma unroll
        for (int nf = 0; nf < 8; nf++) {
          const int row = nf * 16 + lr;
          bf16x8 bv = *(const bf16x8*)(&Vb[c >> 1][row][(((c & 1) * 4 + kg) ^ (row & 7)) * 8]);
          acc_o[nf] = __builtin_amdgcn_mfma_f32_16x16x32_bf16(ap, bv, acc_o[nf], 0, 0, 0);
        }
      }
      ABAR();
    }
    float* op = opart + (long)cch * 4194304;
    #pragma unroll
    for (int nf = 0; nf < 8; nf++)
      #pragma unroll
      for (int r = 0; r < 4; r++)
        op[(long)(bm + w * 16 + kg * 4 + r) * 2048 + h * 128 + nf * 16 + lr] = acc_o[nf][r];
    if (lr == 0) {
      #pragma unroll
      for (int r = 0; r < 4; r++) {
        const int row = bm + w * 16 + kg * 4 + r;
        stm[(cch * 16 + h) * 2048 + row] = m[r];
        stl[(cch * 16 + h) * 2048 + row] = l[r];
      }
    }
    __syncthreads();
  }
}

// combine kv-chunk partials with (m,l) stats -> normalized o bf16
__global__ __launch_bounds__(256) void o_merge2(
    const float* __restrict__ op, const float* __restrict__ stm,
    const float* __restrict__ stl, unsigned short* __restrict__ o) {
  const int i = blockIdx.x * 256 + threadIdx.x;  // 2048*2048
  const int s = i >> 11, c = i & 2047, h = c >> 7;
  const int si = h * 2048 + s;
  const float m1 = stm[si], l1 = stl[si];
  const float m2 = stm[32768 + si], l2 = stl[32768 + si];
  const float M = fmaxf(m1, m2);
  const float w1 = __expf(m1 - M), w2 = __expf(m2 - M);
  const float denom = l1 * w1 + l2 * w2;
  o[i] = f2b((op[i] * w1 + op[i + 4194304] * w2) / denom);
}

// ---------------- MLP scatter-reduce ----------------
__global__ __launch_bounds__(256) void mlp_reduce(
    const float* __restrict__ pt, const float* __restrict__ pa,
    const int* __restrict__ apos, float* __restrict__ h) {
  const int i = blockIdx.x * 256 + threadIdx.x;
  const int r = i >> 11, c = i & 2047;
  const long Z = (long)1 << 22;
  const int ap = apos[r];
  float val;
  if (ap < 0) {
    val = pt[i] + pt[i + Z] + pt[i + 2 * Z] + pt[i + 3 * Z];
  } else {
    const long b = (long)ap * 2048 + c;
    val = 0.f;
    #pragma unroll
    for (int k = 0; k < 8; k++) val += pa[k * Z + b];
  }
  h[i] += val;
}

// ---------------- 2-phase prefetch GEMM, C = A @ Bt^T ----------------
// EPI: 2 silu->bf16 (early-exit M) | 3 f32 += | 7 K-split partial f32 (early-exit M)
//      8 QKV+RoPE fused
template <int BM, int BN, int EPI>
__global__ __launch_bounds__(512) void gemm2(
    const unsigned short* __restrict__ A, int lda, long sAz,
    const unsigned short* __restrict__ Bt, int ldb, long sBz,
    void* __restrict__ Cv, int ldc, long sCz, long sCx, int K, float scale,
    const int* __restrict__ ecnt, int kspl,
    const float* __restrict__ rc, const float* __restrict__ rs,
    unsigned short* __restrict__ kbo, unsigned short* __restrict__ vbo) {
  constexpr int MF = BM / 32;
  constexpr int NF = BN / 64;
  __shared__ __align__(16) unsigned short smem[2 * (BM + BN) * 64];
  const int tid = threadIdx.x;
  const int lane = tid & 63;
  const int wave = tid >> 6;
  const int bm = blockIdx.y * BM;
  const int z = blockIdx.z;
  int bn, kbeg, nt;
  if constexpr (EPI == 7) {
    bn = blockIdx.x * BN;
    kbeg = z * kspl;
    nt = kspl / 64;
  } else {
    bn = blockIdx.x * BN;
    kbeg = 0;
    nt = K / 64;
  }
  if constexpr (EPI == 2 || EPI == 7) {
    if (bm >= ecnt[1]) return;
  }
  A += sAz * z;
  Bt += sBz * z;
  const int wm = (wave >> 2) * (BM / 2);
  const int wn = (wave & 3) * (BN / 4);
  const int lr = lane & 15;
  const int kg = lane >> 4;
  const int swx = lr & 7;
  const int trow = tid >> 3;
  const int tc = tid & 7;
  const long aoff = (long)(bm + trow) * lda + ((tc ^ (trow & 7)) * 8);
  const long boff = (long)(bn + trow) * ldb + ((tc ^ (trow & 7)) * 8);

  f32x4 acc[MF][NF];
  #pragma unroll
  for (int m = 0; m < MF; m++)
    #pragma unroll
    for (int n = 0; n < NF; n++) acc[m][n] = (f32x4){0.f, 0.f, 0.f, 0.f};

  auto stage = [&](int buf, int k0) {
    unsigned short* sA = &smem[(size_t)buf * (BM + BN) * 64];
    #pragma unroll
    for (int r = 0; r < BM / 64; r++)
      gload16(A + aoff + (long)r * 64 * lda + k0, sA + r * 4096 + tid * 8);
    unsigned short* sB = sA + BM * 64;
    #pragma unroll
    for (int r = 0; r < BN / 64; r++)
      gload16(Bt + boff + (long)r * 64 * ldb + k0, sB + r * 4096 + tid * 8);
  };
  auto compute = [&](int buf) {
    const unsigned short* sA = &smem[(size_t)buf * (BM + BN) * 64];
    const unsigned short* sB = sA + BM * 64;
    #pragma unroll
    for (int ks = 0; ks < 2; ks++) {
      bf16x8 af[MF], bv[NF];
      #pragma unroll
      for (int m = 0; m < MF; m++) {
        const int row = wm + m * 16 + lr;
        af[m] = *(const bf16x8*)(sA + row * 64 + (((ks * 4 + kg) ^ swx) * 8));
      }
      #pragma unroll
      for (int n = 0; n < NF; n++) {
        const int row = wn + n * 16 + lr;
        bv[n] = *(const bf16x8*)(sB + row * 64 + (((ks * 4 + kg) ^ swx) * 8));
      }
      #pragma unroll
      for (int m = 0; m < MF; m++)
        #pragma unroll
        for (int n = 0; n < NF; n++)
          acc[m][n] = __builtin_amdgcn_mfma_f32_16x16x32_bf16(af[m], bv[n], acc[m][n], 0, 0, 0);
    }
  };

  if (nt > 0) {
    stage(0, kbeg);
    asm volatile("s_waitcnt vmcnt(0)" ::: "memory");
    __syncthreads();
    int cur = 0;
    for (int t = 0; t < nt; t++) {
      if (t + 1 < nt) stage(cur ^ 1, kbeg + (t + 1) * 64);
      compute(cur);
      asm volatile("s_waitcnt vmcnt(0)" ::: "memory");
      __syncthreads();
      cur ^= 1;
    }
  }

  if constexpr (EPI == 8) {
    if (bn >= 2560) {
      #pragma unroll
      for (int m = 0; m < MF; m++)
        #pragma unroll
        for (int n = 0; n < NF; n++)
          #pragma unroll
          for (int r = 0; r < 4; r++) {
            const int grow = bm + wm + m * 16 + kg * 4 + r;
            const int gcol = bn + wn + n * 16 + lr;
            vbo[(long)grow * 512 + (gcol - 2560)] = f2b(acc[m][n][r]);
          }
    } else {
      float* Cl = (float*)smem;  // [128][128] f32 = 64 KiB
      #pragma unroll
      for (int m = 0; m < MF; m++)
        #pragma unroll
        for (int n = 0; n < NF; n++)
          #pragma unroll
          for (int r = 0; r < 4; r++)
            Cl[(wm + m * 16 + kg * 4 + r) * 128 + wn + n * 16 + lr] = acc[m][n][r];
      __syncthreads();
      const int j = tid & 63;
      const int r2 = tid >> 6;
      #pragma unroll
      for (int it = 0; it < 16; it++) {
        const int row = r2 + it * 8;
        const int s = bm + row;
        const float c = rc[s * 64 + j], sn = rs[s * 64 + j];
        const float x1 = Cl[row * 128 + j], x2 = Cl[row * 128 + j + 64];
        const unsigned short o1 = f2b(x1 * c - x2 * sn);
        const unsigned short o2 = f2b(x2 * c + x1 * sn);
        if (bn < 2048) {
          unsigned short* qp = (unsigned short*)Cv + (long)s * 2048 + bn + j;
          qp[0] = o1; qp[64] = o2;
        } else {
          unsigned short* kp = kbo + (long)s * 512 + (bn - 2048) + j;
          kp[0] = o1; kp[64] = o2;
        }
      }
    }
    return;
  }

  #pragma unroll
  for (int m = 0; m < MF; m++) {
    #pragma unroll
    for (int n = 0; n < NF; n++) {
      #pragma unroll
      for (int r = 0; r < 4; r++) {
        const int grow = bm + wm + m * 16 + kg * 4 + r;
        const int gcol = bn + wn + n * 16 + lr;
        const long idx = (long)grow * ldc + gcol;
        float v = acc[m][n][r];
        if constexpr (EPI == 2) {
          ((unsigned short*)Cv)[idx] = f2b(v / (1.f + expf(-v)));
        } else if constexpr (EPI == 3) {
          ((float*)Cv)[idx] += v;
        } else if constexpr (EPI == 7) {
          ((float*)Cv)[(long)z * sCz + idx] = v;
        }
      }
    }
  }
}

// ---------------- 8-phase 256x256 GEMM, register read-ahead ----------------
// Phases (0,0)(0,1)(1,1)(1,0). af=A0 (read own @P0), af2=A1 (read AHEAD @P1,
// hidden under P1's MFMA), bv1=B1 (read ahead @P0), bv0=B0 (read @P0, re-read
// @P3 so its regs die P1-P2 -> allocator overlaps with af2; keeps unified regs
// ~<=256 for 2 waves/SIMD). Stage schedule: P0->A1(t+1), P1->A0(t+2),
// P2->B1(t+2), P3->B0(t+2) (B0 staged @P3 AFTER its re-read). Uniform
// vmcnt(8) = 4-stage flight; ledger verified for t=0, steady, drain. nt>=3.
template <int EPI>
__global__ __launch_bounds__(512, 1) void gemm8(
    const unsigned short* __restrict__ A0, const unsigned short* __restrict__ A1, int lda,
    const unsigned short* __restrict__ Bt, long sBz, int ldb,
    void* __restrict__ Cv, int ldc, long sCz, int K) {
  __shared__ __align__(16) unsigned short smem[2][4][8192];
  const int tid = threadIdx.x;
  const int lane = tid & 63;
  const int wave = tid >> 6;
  const int bm = blockIdx.y * 256;
  const int bn = blockIdx.x * 256;
  const int z = blockIdx.z;
  const unsigned short* Aq;
  const unsigned short* Bq;
  if constexpr (EPI == 10) {
    Aq = z ? A1 : A0;
    Bq = Bt + (long)z * sBz;
  } else {
    Aq = A0 + z * 2048;
    Bq = Bt + z * 2048;
  }
  const int nt = K / 64;
  const int trow = tid >> 3;
  const int tc = tid & 7;
  const int sws = (tc ^ (trow & 7)) * 8;
  const int lr = lane & 15;
  const int kg = lane >> 4;
  const int wr = (wave >> 2) * 64;
  const int wc = (wave & 3) * 32;

  f32x4 acc[2][2][4][2];
  #pragma unroll
  for (int mh = 0; mh < 2; mh++)
    #pragma unroll
    for (int nh = 0; nh < 2; nh++)
      #pragma unroll
      for (int mf = 0; mf < 4; mf++)
        #pragma unroll
        for (int nf = 0; nf < 2; nf++) acc[mh][nh][mf][nf] = (f32x4){0.f, 0.f, 0.f, 0.f};

  bf16x8 af[2][4], af2[2][4], bv0[2][2], bv1[2][2];

  auto stageA = [&](int buf, int half, int k0) {
    const unsigned short* g = Aq + (long)(bm + half * 128 + trow) * lda + k0 + sws;
    unsigned short* l = &smem[buf][half][0] + tid * 8;
    gload16(g, l);
    gload16(g + (long)64 * lda, l + 4096);
  };
  auto stageB = [&](int buf, int half, int k0) {
    const unsigned short* g = Bq + (long)(bn + half * 128 + trow) * ldb + k0 + sws;
    unsigned short* l = &smem[buf][2 + half][0] + tid * 8;
    gload16(g, l);
    gload16(g + (long)64 * ldb, l + 4096);
  };

#define GSYNC(VM) \
  asm volatile("s_waitcnt vmcnt(" #VM ")" ::: "memory"); \
  __builtin_amdgcn_s_barrier(); \
  asm volatile("" ::: "memory"); \
  __builtin_amdgcn_sched_barrier(0)

#define RD_A(BUF, MH, DST) do { \
    _Pragma("unroll") \
    for (int ks = 0; ks < 2; ++ks) { \
      _Pragma("unroll") \
      for (int mf = 0; mf < 4; ++mf) { \
        const int row = wr + mf * 16 + lr; \
        DST[ks][mf] = *(const bf16x8*)(&smem[BUF][MH][0] + row * 64 + (((ks * 4 + kg) ^ (row & 7)) * 8)); \
      } \
    } \
  } while (0)

#define RD_B(BUF, NH, DST) do { \
    _Pragma("unroll") \
    for (int ks = 0; ks < 2; ++ks) { \
      _Pragma("unroll") \
      for (int nf = 0; nf < 2; ++nf) { \
        const int row = wc + nf * 16 + lr; \
        DST[ks][nf] = *(const bf16x8*)(&smem[BUF][2 + NH][0] + row * 64 + (((ks * 4 + kg) ^ (row & 7)) * 8)); \
      } \
    } \
  } while (0)

#define DO_MFMA(MH, NH, AF, BV) do { \
    __builtin_amdgcn_s_setprio(1); \
    _Pragma("unroll") \
    for (int ks = 0; ks < 2; ++ks) \
      _Pragma("unroll") \
      for (int mf = 0; mf < 4; ++mf) \
        _Pragma("unroll") \
        for (int nf = 0; nf < 2; ++nf) \
          acc[MH][NH][mf][nf] = __builtin_amdgcn_mfma_f32_16x16x32_bf16( \
              AF[ks][mf], BV[ks][nf], acc[MH][NH][mf][nf], 0, 0, 0); \
    __builtin_amdgcn_s_setprio(0); \
  } while (0)

  // prologue: A0(0),B0(0),B1(0),A1(0),A0(1),B1(1),B0(1); vmcnt(8) retires first 3
  stageA(0, 0, 0); stageB(0, 0, 0); stageB(0, 1, 0); stageA(0, 1, 0);
  stageA(1, 0, 64); stageB(1, 1, 64); stageB(1, 0, 64);
  GSYNC(8);

  for (int t = 0; t <= nt - 3; ++t) {
    const int b = t & 1, nb = b ^ 1;
    const int k1 = (t + 1) << 6, k2 = (t + 2) << 6;
    RD_A(b, 0, af); RD_B(b, 0, bv0); RD_B(b, 1, bv1);
    stageA(nb, 1, k1); DO_MFMA(0, 0, af, bv0); GSYNC(8);
    RD_A(b, 1, af2);
    stageA(b, 0, k2); DO_MFMA(0, 1, af, bv1); GSYNC(8);
    stageB(b, 1, k2); DO_MFMA(1, 1, af2, bv1); GSYNC(8);
    RD_B(b, 0, bv0);
    stageB(b, 0, k2); DO_MFMA(1, 0, af2, bv0); GSYNC(8);
  }
  {
    const int t = nt - 2;
    const int b = t & 1, nb = b ^ 1;
    const int k1 = (t + 1) << 6;
    RD_A(b, 0, af); RD_B(b, 0, bv0); RD_B(b, 1, bv1);
    stageA(nb, 1, k1); DO_MFMA(0, 0, af, bv0); GSYNC(8);
    RD_A(b, 1, af2); DO_MFMA(0, 1, af, bv1); GSYNC(8);
    DO_MFMA(1, 1, af2, bv1); GSYNC(8);
    RD_B(b, 0, bv0); DO_MFMA(1, 0, af2, bv0); GSYNC(2);
  }
  {
    const int b = (nt - 1) & 1;
    RD_A(b, 0, af); RD_B(b, 0, bv0); RD_B(b, 1, bv1);
    DO_MFMA(0, 0, af, bv0); GSYNC(0);
    RD_A(b, 1, af2); DO_MFMA(0, 1, af, bv1);
    DO_MFMA(1, 1, af2, bv1);
    RD_B(b, 0, bv0); DO_MFMA(1, 0, af2, bv0);
  }
#undef DO_MFMA
#undef RD_B
#undef RD_A
#undef GSYNC

  #pragma unroll
  for (int mh = 0; mh < 2; mh++) {
    #pragma unroll
    for (int nh = 0; nh < 2; nh++) {
      #pragma unroll
      for (int mf = 0; mf < 4; mf++) {
        #pragma unroll
        for (int nf = 0; nf < 2; nf++) {
          #pragma unroll
          for (int r = 0; r < 4; r++) {
            const int grow = bm + mh * 128 + wr + mf * 16 + kg * 4 + r;
            const int gcol = bn + nh * 128 + wc + nf * 16 + lr;
            const long idx = (long)z * sCz + (long)grow * ldc + gcol;
            const float v = acc[mh][nh][mf][nf][r];
            if constexpr (EPI == 10) {
              ((unsigned short*)Cv)[idx] = f2b(v / (1.f + expf(-v)));
            } else {
              ((float*)Cv)[idx] = v;
            }
          }
        }
      }
    }
  }
}

__global__ __launch_bounds__(256) void fill_zero(float* p, long n) {
  const long i = (long)blockIdx.x * 256 + threadIdx.x;
  if (i < n) p[i] = 0.f;
}

extern "C" void kernel_launch(void* const* d_in, const int* in_sizes, int n_in,
                              void* d_out, int out_size, void* d_ws, size_t ws_size,
                              hipStream_t stream) {
  const int* ids = (const int*)d_in[0];
  const float* vocab_emb = (const float*)d_in[1];
  const float* audio_emb = (const float*)d_in[2];
  const float* ln_in_text = (const float*)d_in[3];
  const float* ln_in_audio = (const float*)d_in[4];
  const float* ln_post_text = (const float*)d_in[5];
  const float* ln_post_audio = (const float*)d_in[6];
  const float* wq = (const float*)d_in[7];
  const float* wk = (const float*)d_in[8];
  const float* wv = (const float*)d_in[9];
  const float* wo = (const float*)d_in[10];
  const float* wfc_t = (const float*)d_in[11];
  const float* wpj_t = (const float*)d_in[12];
  const float* wfc_a = (const float*)d_in[13];
  const float* wpj_a = (const float*)d_in[14];
  const float* ln_f = (const float*)d_in[15];

  size_t off = 0;
  auto alloc = [&](size_t bytes) -> void* {
    void* p = (char*)d_ws + off;
    off += (bytes + 255) & ~(size_t)255;
    return p;
  };
  const size_t LW = 77594624;
  unsigned short* wsT = (unsigned short*)alloc((size_t)2 * LW * 2);
  int* amask = (int*)alloc(S_LEN * 4);
  int* apos = (int*)alloc(S_LEN * 4);
  int* cnt = (int*)alloc(16);
  int* ctrs = (int*)alloc(16);
  float* ropec = (float*)alloc((size_t)S_LEN * 64 * 4);
  float* ropes = (float*)alloc((size_t)S_LEN * 64 * 4);
  float* h = (float*)alloc((size_t)S_LEN * HID * 4);
  unsigned short* hn = (unsigned short*)alloc((size_t)S_LEN * HID * 2);
  unsigned short* hnt = (unsigned short*)alloc((size_t)S_LEN * HID * 2);
  unsigned short* hna_g = (unsigned short*)alloc((size_t)S_LEN * HID * 2);
  unsigned short* qb = (unsigned short*)alloc((size_t)S_LEN * 2048 * 2);
  unsigned short* kb = (unsigned short*)alloc((size_t)S_LEN * 512 * 2);
  unsigned short* vb = (unsigned short*)alloc((size_t)S_LEN * 512 * 2);
  unsigned short* vt = (unsigned short*)alloc((size_t)512 * S_LEN * 2);
  unsigned short* o = (unsigned short*)alloc((size_t)S_LEN * 2048 * 2);
  float* stm = (float*)alloc((size_t)2 * 16 * 2048 * 4);
  float* stl = (float*)alloc((size_t)2 * 16 * 2048 * 4);
  char* big = (char*)alloc(268435456);
  float* opart = (float*)big;                      // [2][2048][2048] f32
  unsigned short* mlp_t = (unsigned short*)big;
  unsigned short* mlp_a = (unsigned short*)(big + 33554432);
  float* pt = (float*)(big + 67108864);
  float* pa = (float*)(big + 134217728);

  if (ws_size < off) {
    fill_zero<<<(out_size + 255) / 256, 256, 0, stream>>>((float*)d_out, out_size);
    return;
  }

  const size_t WO_ = 6291456, WFT = 10485760, WPT = 27262976, WFA = 44040192, WPA = 60817408;

  embed_kernel<<<S_LEN, 256, 0, stream>>>(ids, vocab_emb, audio_emb, h, amask);
  partition_rows<<<1, 256, 0, stream>>>(ids, apos, cnt);
  init_ctrs<<<1, 4, 0, stream>>>(ctrs);
  init_stats<<<256, 256, 0, stream>>>(stm, stl);
  rope_table<<<S_LEN * 64 / 256, 256, 0, stream>>>(ropec, ropes);

  for (int i = 0; i < 2; i++) {
    const size_t wb = (size_t)i * LW;
    transposew<<<dim3(32, 32), 256, 0, stream>>>(wq + (size_t)i * 2048 * 2048, 2048, wsT + wb, 2048, 2048);
    transposew<<<dim3(8, 32), 256, 0, stream>>>(wk + (size_t)i * 2048 * 512, 512, wsT + wb + 4194304, 2048, 512);
    transposew<<<dim3(8, 32), 256, 0, stream>>>(wv + (size_t)i * 2048 * 512, 512, wsT + wb + 5242880, 2048, 512);
    transposew<<<dim3(32, 32), 256, 0, stream>>>(wo + (size_t)i * 2048 * 2048, 2048, wsT + wb + WO_, 2048, 2048);
    transposew<<<dim3(128, 32), 256, 0, stream>>>(wfc_t + (size_t)i * 2048 * 8192, 8192, wsT + wb + WFT, 2048, 8192);
    transposew<<<dim3(32, 128), 256, 0, stream>>>(wpj_t + (size_t)i * 8192 * 2048, 2048, wsT + wb + WPT, 8192, 2048);
    transposew<<<dim3(128, 32), 256, 0, stream>>>(wfc_a + (size_t)i * 2048 * 8192, 8192, wsT + wb + WFA, 2048, 8192);
    transposew<<<dim3(32, 128), 256, 0, stream>>>(wpj_a + (size_t)i * 8192 * 2048, 2048, wsT + wb + WPA, 8192, 2048);
  }

  const float iscale = 0.08838834764831845f;  // 1/sqrt(128)
  for (int i = 0; i < 2; i++) {
    const size_t wb = (size_t)i * LW;
    rmsnorm_sel<<<S_LEN, 256, 0, stream>>>(h, amask, ln_in_text + i * HID, ln_in_audio + i * HID, hn);
    gemm2<128, 128, 8><<<dim3(24, 16, 1), 512, 0, stream>>>(hn, 2048, 0, wsT + wb, 2048, 0,
        qb, 2048, 0, 0, 2048, 1.f, nullptr, 0, ropec, ropes, kb, vb);
    transpose_b16<<<dim3(8, 32), 256, 0, stream>>>(vb, vt);
    attn_flash<<<256, 512, 0, stream>>>(qb, kb, vt, opart, stm, stl, ctrs + i, iscale);
    o_merge2<<<16384, 256, 0, stream>>>(opart, stm, stl, o);
    gemm2<128, 128, 3><<<dim3(16, 16, 1), 512, 0, stream>>>(o, 2048, 0, wsT + wb + WO_, 2048, 0,
        h, 2048, 0, 0, 2048, 1.f, nullptr, 0, nullptr, nullptr, nullptr, nullptr);
    rmsnorm_post<<<S_LEN, 256, 0, stream>>>(h, apos, ln_post_text + i * HID, ln_post_audio + i * HID, hnt, hna_g);
    gemm2<128, 128, 2><<<dim3(64, 16, 1), 512, 0, stream>>>(hna_g, 2048, 0, wsT + wb + WFA, 2048, 0,
        mlp_a, 8192, 0, 0, 2048, 1.f, cnt, 0, nullptr, nullptr, nullptr, nullptr);
    gemm8<10><<<dim3(32, 8, 1), 512, 0, stream>>>(hnt, hnt, 2048, wsT + wb + WFT, 0, 2048,
        mlp_t, 8192, 0, 2048);
    gemm2<128, 128, 7><<<dim3(16, 16, 8), 512, 0, stream>>>(mlp_a, 8192, 0, wsT + wb + WPA, 8192, 0,
        pa, 2048, (long)1 << 22, 0, 8192, 1.f, cnt, 1024, nullptr, nullptr, nullptr, nullptr);
    gemm8<11><<<dim3(8, 8, 4), 512, 0, stream>>>(mlp_t, mlp_t, 8192, wsT + wb + WPT, 0, 8192,
        pt, 2048, (long)1 << 22, 2048);
    mlp_reduce<<<16384, 256, 0, stream>>>(pt, pa, apos, h);
  }
  rmsnorm_final<<<S_LEN, 256, 0, stream>>>(h, ln_f, (float*)d_out);
}

// Round 11
// 968.284 us; speedup vs baseline: 1.0213x; 1.0213x over previous
//
#include <hip/hip_runtime.h>
#include <hip/hip_bf16.h>
#include <math.h>

#define S_LEN 2048
#define HID   2048

typedef __bf16 bf16x8 __attribute__((ext_vector_type(8)));
typedef float  f32x4  __attribute__((ext_vector_type(4)));

__device__ __forceinline__ unsigned short f2b(float x) {
  __hip_bfloat16 h = __float2bfloat16(x);
  return __builtin_bit_cast(unsigned short, h);
}

__device__ __forceinline__ float block_sum_256(float v) {
  __shared__ float red[4];
  #pragma unroll
  for (int o = 32; o > 0; o >>= 1) v += __shfl_down(v, o, 64);
  if ((threadIdx.x & 63) == 0) red[threadIdx.x >> 6] = v;
  __syncthreads();
  v = red[0] + red[1] + red[2] + red[3];
  __syncthreads();
  return v;
}

// ---------------- embedding ----------------
__global__ __launch_bounds__(256) void embed_kernel(
    const int* __restrict__ ids, const float* __restrict__ vemb,
    const float* __restrict__ aemb, float* __restrict__ h, int* __restrict__ amask) {
  const int s = blockIdx.x;
  const int id = ids[s];
  const bool am = id > 31999;
  if (threadIdx.x == 0) amask[s] = am ? 1 : 0;
  const int d0 = threadIdx.x * 8;
  float out[8];
  if (am) {
    const int at = id - 32000;
    #pragma unroll
    for (int u = 0; u < 8; u++) out[u] = 0.f;
    for (int cb = 0; cb < 8; cb++) {
      const float* src = aemb + (long)(at + cb * 1024) * HID + d0;
      #pragma unroll
      for (int u = 0; u < 8; u++) out[u] += src[u];
    }
  } else {
    const float* src = vemb + (long)id * HID + d0;
    #pragma unroll
    for (int u = 0; u < 8; u++) out[u] = src[u];
  }
  float* dst = h + (long)s * HID + d0;
  #pragma unroll
  for (int u = 0; u < 8; u++) dst[u] = out[u];
}

// ---------------- row partition ----------------
__global__ __launch_bounds__(256) void partition_rows(
    const int* __restrict__ ids, int* __restrict__ apos, int* __restrict__ cnt) {
  __shared__ int ca[256];
  __shared__ int sc[257];
  const int t = threadIdx.x;
  int m[8], loc = 0;
  #pragma unroll
  for (int i = 0; i < 8; i++) { m[i] = ids[t * 8 + i] > 31999 ? 1 : 0; loc += m[i]; }
  ca[t] = loc;
  __syncthreads();
  if (t == 0) {
    int run = 0;
    for (int i = 0; i < 256; i++) { sc[i] = run; run += ca[i]; }
    sc[256] = run;
  }
  __syncthreads();
  int off = sc[t];
  #pragma unroll
  for (int i = 0; i < 8; i++) {
    const int s = t * 8 + i;
    if (m[i]) { apos[s] = off; off++; }
    else apos[s] = -1;
  }
  if (t == 0) { cnt[0] = sc[256]; cnt[1] = (sc[256] + 127) & ~127; }
}

__global__ __launch_bounds__(256) void init_stats(
    float* __restrict__ stm, float* __restrict__ stl, int* __restrict__ ctrs) {
  const int i = blockIdx.x * 256 + threadIdx.x;  // 65536 = 2*16*2048
  stm[i] = -1e30f;
  stl[i] = 0.f;
  if (i < 4) ctrs[i] = 0;
}

// ---------------- weight transpose + f32->bf16 (64x64 tile, float4, z=layer) ----------------
__global__ __launch_bounds__(256) void transposew(
    const float* __restrict__ W, int ldw, unsigned short* __restrict__ Wt, int K, int N,
    long srcZ, long dstZ) {
  W += (long)blockIdx.z * srcZ;
  Wt += (long)blockIdx.z * dstZ;
  __shared__ float t[64][65];
  const int k0 = blockIdx.y * 64, n0 = blockIdx.x * 64;
  const int q = threadIdx.x & 15;
  const int r0 = threadIdx.x >> 4;
  #pragma unroll
  for (int i = 0; i < 4; i++) {
    const int row = r0 + i * 16;
    const float4 v = *(const float4*)(W + (long)(k0 + row) * ldw + n0 + q * 4);
    t[row][q * 4 + 0] = v.x; t[row][q * 4 + 1] = v.y;
    t[row][q * 4 + 2] = v.z; t[row][q * 4 + 3] = v.w;
  }
  __syncthreads();
  #pragma unroll
  for (int i = 0; i < 4; i++) {
    const int n = r0 + i * 16;
    ushort4 o;
    o.x = f2b(t[q * 4 + 0][n]); o.y = f2b(t[q * 4 + 1][n]);
    o.z = f2b(t[q * 4 + 2][n]); o.w = f2b(t[q * 4 + 3][n]);
    *(ushort4*)(Wt + (long)(n0 + n) * K + k0 + q * 4) = o;
  }
}

// bf16 transpose: V [2048][512] -> Vt [512][2048]
__global__ __launch_bounds__(256) void transpose_b16(
    const unsigned short* __restrict__ V, unsigned short* __restrict__ Vt) {
  __shared__ unsigned short t[64][72];
  const int s0 = blockIdx.y * 64, d0 = blockIdx.x * 64;
  const int q = threadIdx.x & 15;
  const int r0 = threadIdx.x >> 4;
  #pragma unroll
  for (int i = 0; i < 4; i++) {
    const int row = r0 + i * 16;
    const ushort4 v = *(const ushort4*)(V + (long)(s0 + row) * 512 + d0 + q * 4);
    t[row][q * 4 + 0] = v.x; t[row][q * 4 + 1] = v.y;
    t[row][q * 4 + 2] = v.z; t[row][q * 4 + 3] = v.w;
  }
  __syncthreads();
  #pragma unroll
  for (int i = 0; i < 4; i++) {
    const int d = r0 + i * 16;
    ushort4 o;
    o.x = t[q * 4 + 0][d]; o.y = t[q * 4 + 1][d];
    o.z = t[q * 4 + 2][d]; o.w = t[q * 4 + 3][d];
    *(ushort4*)(Vt + (long)(d0 + d) * 2048 + s0 + q * 4) = o;
  }
}

// ---------------- RoPE table ----------------
__global__ __launch_bounds__(256) void rope_table(float* __restrict__ c, float* __restrict__ s_) {
  const int i = blockIdx.x * 256 + threadIdx.x;
  const int pos = i >> 6, j = i & 63;
  const float inv = powf(10000.f, -(float)(2 * j) * (1.f / 128.f));
  const float ang = (float)pos * inv;
  c[i] = cosf(ang);
  s_[i] = sinf(ang);
}

// ---------------- RMSNorms ----------------
__global__ __launch_bounds__(256) void rmsnorm_sel(
    const float* __restrict__ x, const int* __restrict__ amask,
    const float* __restrict__ wt, const float* __restrict__ wa, unsigned short* __restrict__ out) {
  const long s = blockIdx.x;
  const float* xr = x + s * HID;
  const int d0 = threadIdx.x * 8;
  float v[8], ss = 0.f;
  #pragma unroll
  for (int u = 0; u < 8; u++) { v[u] = xr[d0 + u]; ss += v[u] * v[u]; }
  ss = block_sum_256(ss) * (1.f / HID);
  const float rr = rsqrtf(ss + 1e-5f);
  const float* w = amask[s] ? wa : wt;
  #pragma unroll
  for (int u = 0; u < 8; u++) out[s * HID + d0 + u] = f2b(v[u] * rr * w[d0 + u]);
}

__global__ __launch_bounds__(256) void rmsnorm_post(
    const float* __restrict__ x, const int* __restrict__ apos,
    const float* __restrict__ wt, const float* __restrict__ wa,
    unsigned short* __restrict__ hnt, unsigned short* __restrict__ hna_g) {
  const long s = blockIdx.x;
  const float* xr = x + s * HID;
  const int d0 = threadIdx.x * 8;
  float v[8], ss = 0.f;
  #pragma unroll
  for (int u = 0; u < 8; u++) { v[u] = xr[d0 + u]; ss += v[u] * v[u]; }
  ss = block_sum_256(ss) * (1.f / HID);
  const float rr = rsqrtf(ss + 1e-5f);
  const int ap = apos[s];
  #pragma unroll
  for (int u = 0; u < 8; u++) {
    const float xn = v[u] * rr;
    hnt[s * HID + d0 + u] = f2b(xn * wt[d0 + u]);
    if (ap >= 0) hna_g[(long)ap * HID + d0 + u] = f2b(xn * wa[d0 + u]);
  }
}

__global__ __launch_bounds__(256) void rmsnorm_final(
    const float* __restrict__ x, const float* __restrict__ w, float* __restrict__ out) {
  const long s = blockIdx.x;
  const float* xr = x + s * HID;
  const int d0 = threadIdx.x * 8;
  float v[8], ss = 0.f;
  #pragma unroll
  for (int u = 0; u < 8; u++) { v[u] = xr[d0 + u]; ss += v[u] * v[u]; }
  ss = block_sum_256(ss) * (1.f / HID);
  const float rr = rsqrtf(ss + 1e-5f);
  #pragma unroll
  for (int u = 0; u < 8; u++) out[s * HID + d0 + u] = v[u] * rr * w[d0 + u];
}

__device__ __forceinline__ void gload16(const void* g, void* l) {
  __builtin_amdgcn_global_load_lds((const __attribute__((address_space(1))) void*)g,
                                   (__attribute__((address_space(3))) void*)l, 16, 0, 0);
}

#define ABAR() do { __builtin_amdgcn_s_barrier(); \
  asm volatile("" ::: "memory"); __builtin_amdgcn_sched_barrier(0); } while (0)

// ---------------- single-pass flash attention (kv-chunked) ----------------
__global__ __launch_bounds__(512, 1) void attn_flash(
    const unsigned short* __restrict__ qb, const unsigned short* __restrict__ kb,
    const unsigned short* __restrict__ vt, float* __restrict__ opart,
    float* __restrict__ stm, float* __restrict__ stl,
    int* __restrict__ ctr, float iscale) {
  __shared__ __align__(16) unsigned short Kb[2][2][128][64];
  __shared__ __align__(16) unsigned short Vb[2][128][64];
  __shared__ __align__(16) unsigned short Pb[8][16][144];
  __shared__ int s_item;
  const int tid = threadIdx.x;
  const int lane = tid & 63;
  const int w = tid >> 6;
  const int lr = lane & 15;
  const int kg = lane >> 4;
  const int trow = tid >> 3;
  const int tc = tid & 7;

  for (;;) {
    if (tid == 0) s_item = atomicAdd(ctr, 1);
    __syncthreads();
    const int item = s_item;
    __syncthreads();
    if (item >= 512) break;
    const int qq = 15 - (item >> 5);
    const int h = item & 15;
    const int cch = (item >> 4) & 1;
    const int kvh = h >> 2;
    const int bm = qq * 128;
    const int nt = qq + 1;
    const int tmid = (nt + 1) >> 1;
    const int t0 = cch ? tmid : 0;
    const int t1 = cch ? nt : tmid;
    if (t0 >= t1) continue;

    bf16x8 af_q[4];
    {
      const unsigned short* qr = qb + (long)(bm + w * 16 + lr) * 2048 + h * 128 + kg * 8;
      #pragma unroll
      for (int c = 0; c < 4; c++) af_q[c] = *(const bf16x8*)(qr + c * 32);
    }
    float m[4], l[4];
    #pragma unroll
    for (int r = 0; r < 4; r++) { m[r] = -1e30f; l[r] = 0.f; }
    f32x4 acc_o[8];
    #pragma unroll
    for (int nf = 0; nf < 8; nf++) acc_o[nf] = (f32x4){0.f, 0.f, 0.f, 0.f};

    auto stageK = [&](int buf, int t) {
      const int kv0 = t * 128;
      #pragma unroll
      for (int hh2 = 0; hh2 < 2; hh2++)
        #pragma unroll
        for (int rr = 0; rr < 2; rr++) {
          const int row = trow + rr * 64;
          gload16(kb + (long)(kv0 + row) * 512 + kvh * 128 + hh2 * 64 + ((tc ^ (row & 7)) * 8),
                  &Kb[buf][hh2][row][tc * 8]);
        }
    };
    auto stageV = [&](int t) {
      const int kv0 = t * 128;
      #pragma unroll
      for (int hh2 = 0; hh2 < 2; hh2++)
        #pragma unroll
        for (int rr = 0; rr < 2; rr++) {
          const int row = trow + rr * 64;
          gload16(vt + (long)(kvh * 128 + row) * 2048 + kv0 + hh2 * 64 + ((tc ^ (row & 7)) * 8),
                  &Vb[hh2][row][tc * 8]);
        }
    };

    stageK(t0 & 1, t0);
    for (int t = t0; t < t1; t++) {
      const bool hn = (t + 1) < t1;
      stageV(t);
      if (hn) stageK((t + 1) & 1, t + 1);
      if (hn) { asm volatile("s_waitcnt vmcnt(8)" ::: "memory"); }
      else    { asm volatile("s_waitcnt vmcnt(4)" ::: "memory"); }
      ABAR();
      f32x4 acc[8];
      #pragma unroll
      for (int nf = 0; nf < 8; nf++) acc[nf] = (f32x4){0.f, 0.f, 0.f, 0.f};
      #pragma unroll
      for (int c = 0; c < 4; c++) {
        #pragma unroll
        for (int nf = 0; nf < 8; nf++) {
          const int row = nf * 16 + lr;
          bf16x8 bk = *(const bf16x8*)(&Kb[t & 1][c >> 1][row][(((c & 1) * 4 + kg) ^ (row & 7)) * 8]);
          acc[nf] = __builtin_amdgcn_mfma_f32_16x16x32_bf16(af_q[c], bk, acc[nf], 0, 0, 0);
        }
      }
      const bool diag = (t == nt - 1);
      #pragma unroll
      for (int r = 0; r < 4; r++) {
        const int rowg = bm + w * 16 + kg * 4 + r;
        float sv[8], tmax = -1e30f;
        #pragma unroll
        for (int nf = 0; nf < 8; nf++) {
          float s = acc[nf][r] * iscale;
          const int colg = t * 128 + nf * 16 + lr;
          if (diag && colg > rowg) s = -1e30f;
          sv[nf] = s;
          tmax = fmaxf(tmax, s);
        }
        #pragma unroll
        for (int o = 1; o < 16; o <<= 1) tmax = fmaxf(tmax, __shfl_xor(tmax, o, 64));
        const float mn = fmaxf(m[r], tmax);
        const float scal = __expf(m[r] - mn);
        float psum = 0.f;
        #pragma unroll
        for (int nf = 0; nf < 8; nf++) {
          const float pe = __expf(sv[nf] - mn);
          psum += pe;
          Pb[w][kg * 4 + r][nf * 16 + lr] = f2b(pe);
        }
        #pragma unroll
        for (int o = 1; o < 16; o <<= 1) psum += __shfl_xor(psum, o, 64);
        l[r] = l[r] * scal + psum;
        m[r] = mn;
        #pragma unroll
        for (int nf = 0; nf < 8; nf++) acc_o[nf][r] *= scal;
      }
      asm volatile("s_waitcnt lgkmcnt(0)" ::: "memory");
      __builtin_amdgcn_sched_barrier(0);
      if (hn) { asm volatile("s_waitcnt vmcnt(4)" ::: "memory"); }
      else    { asm volatile("s_waitcnt vmcnt(0)" ::: "memory"); }
      ABAR();
      #pragma unroll
      for (int c = 0; c < 4; c++) {
        bf16x8 ap = *(const bf16x8*)(&Pb[w][lr][c * 32 + kg * 8]);
        #pragma unroll
        for (int nf = 0; nf < 8; nf++) {
          const int row = nf * 16 + lr;
          bf16x8 bv = *(const bf16x8*)(&Vb[c >> 1][row][(((c & 1) * 4 + kg) ^ (row & 7)) * 8]);
          acc_o[nf] = __builtin_amdgcn_mfma_f32_16x16x32_bf16(ap, bv, acc_o[nf], 0, 0, 0);
        }
      }
      ABAR();
    }
    float* op = opart + (long)cch * 4194304;
    #pragma unroll
    for (int nf = 0; nf < 8; nf++)
      #pragma unroll
      for (int r = 0; r < 4; r++)
        op[(long)(bm + w * 16 + kg * 4 + r) * 2048 + h * 128 + nf * 16 + lr] = acc_o[nf][r];
    if (lr == 0) {
      #pragma unroll
      for (int r = 0; r < 4; r++) {
        const int row = bm + w * 16 + kg * 4 + r;
        stm[(cch * 16 + h) * 2048 + row] = m[r];
        stl[(cch * 16 + h) * 2048 + row] = l[r];
      }
    }
    __syncthreads();
  }
}

// combine kv-chunk partials with (m,l) stats -> normalized o bf16
__global__ __launch_bounds__(256) void o_merge2(
    const float* __restrict__ op, const float* __restrict__ stm,
    const float* __restrict__ stl, unsigned short* __restrict__ o) {
  const int i = blockIdx.x * 256 + threadIdx.x;  // 2048*2048
  const int s = i >> 11, c = i & 2047, h = c >> 7;
  const int si = h * 2048 + s;
  const float m1 = stm[si], l1 = stl[si];
  const float m2 = stm[32768 + si], l2 = stl[32768 + si];
  const float M = fmaxf(m1, m2);
  const float w1 = __expf(m1 - M), w2 = __expf(m2 - M);
  const float denom = l1 * w1 + l2 * w2;
  o[i] = f2b((op[i] * w1 + op[i + 4194304] * w2) / denom);
}

// ---------------- MLP scatter-reduce ----------------
__global__ __launch_bounds__(256) void mlp_reduce(
    const float* __restrict__ pt, const float* __restrict__ pa,
    const int* __restrict__ apos, float* __restrict__ h) {
  const int i = blockIdx.x * 256 + threadIdx.x;
  const int r = i >> 11, c = i & 2047;
  const long Z = (long)1 << 22;
  const int ap = apos[r];
  float val;
  if (ap < 0) {
    val = pt[i] + pt[i + Z] + pt[i + 2 * Z] + pt[i + 3 * Z];
  } else {
    const long b = (long)ap * 2048 + c;
    val = 0.f;
    #pragma unroll
    for (int k = 0; k < 8; k++) val += pa[k * Z + b];
  }
  h[i] += val;
}

// XCD-aware bijective block swizzle over flattened grid (requires nwg % 8 == 0)
__device__ __forceinline__ void xcd_swizzle(int& bx, int& by, int& bz) {
  const int gx = gridDim.x, gy = gridDim.y;
  const long nwg = (long)gx * gy * gridDim.z;
  const long lin = blockIdx.x + (long)gx * (blockIdx.y + (long)gy * blockIdx.z);
  const long cpx = nwg >> 3;
  const long w = (lin & 7) * cpx + (lin >> 3);
  bx = (int)(w % gx);
  const long t = w / gx;
  by = (int)(t % gy);
  bz = (int)(t / gy);
}

// ---------------- 2-phase prefetch GEMM, C = A @ Bt^T ----------------
// EPI: 2 silu->bf16 (early-exit M) | 3 f32 += | 7 K-split partial f32 (early-exit M)
//      8 QKV+RoPE fused. SWZ: XCD-aware block swizzle (grid must be %8==0).
template <int BM, int BN, int EPI, int SWZ>
__global__ __launch_bounds__(512) void gemm2(
    const unsigned short* __restrict__ A, int lda, long sAz,
    const unsigned short* __restrict__ Bt, int ldb, long sBz,
    void* __restrict__ Cv, int ldc, long sCz, long sCx, int K, float scale,
    const int* __restrict__ ecnt, int kspl,
    const float* __restrict__ rc, const float* __restrict__ rs,
    unsigned short* __restrict__ kbo, unsigned short* __restrict__ vbo) {
  constexpr int MF = BM / 32;
  constexpr int NF = BN / 64;
  __shared__ __align__(16) unsigned short smem[2 * (BM + BN) * 64];
  const int tid = threadIdx.x;
  const int lane = tid & 63;
  const int wave = tid >> 6;
  int bxi = blockIdx.x, byi = blockIdx.y, bzi = blockIdx.z;
  if constexpr (SWZ) xcd_swizzle(bxi, byi, bzi);
  const int bm = byi * BM;
  const int z = bzi;
  int bn, kbeg, nt;
  if constexpr (EPI == 7) {
    bn = bxi * BN;
    kbeg = z * kspl;
    nt = kspl / 64;
  } else {
    bn = bxi * BN;
    kbeg = 0;
    nt = K / 64;
  }
  if constexpr (EPI == 2 || EPI == 7) {
    if (bm >= ecnt[1]) return;
  }
  A += sAz * z;
  Bt += sBz * z;
  const int wm = (wave >> 2) * (BM / 2);
  const int wn = (wave & 3) * (BN / 4);
  const int lr = lane & 15;
  const int kg = lane >> 4;
  const int swx = lr & 7;
  const int trow = tid >> 3;
  const int tc = tid & 7;
  const long aoff = (long)(bm + trow) * lda + ((tc ^ (trow & 7)) * 8);
  const long boff = (long)(bn + trow) * ldb + ((tc ^ (trow & 7)) * 8);

  f32x4 acc[MF][NF];
  #pragma unroll
  for (int m = 0; m < MF; m++)
    #pragma unroll
    for (int n = 0; n < NF; n++) acc[m][n] = (f32x4){0.f, 0.f, 0.f, 0.f};

  auto stage = [&](int buf, int k0) {
    unsigned short* sA = &smem[(size_t)buf * (BM + BN) * 64];
    #pragma unroll
    for (int r = 0; r < BM / 64; r++)
      gload16(A + aoff + (long)r * 64 * lda + k0, sA + r * 4096 + tid * 8);
    unsigned short* sB = sA + BM * 64;
    #pragma unroll
    for (int r = 0; r < BN / 64; r++)
      gload16(Bt + boff + (long)r * 64 * ldb + k0, sB + r * 4096 + tid * 8);
  };
  auto compute = [&](int buf) {
    const unsigned short* sA = &smem[(size_t)buf * (BM + BN) * 64];
    const unsigned short* sB = sA + BM * 64;
    #pragma unroll
    for (int ks = 0; ks < 2; ks++) {
      bf16x8 af[MF], bv[NF];
      #pragma unroll
      for (int m = 0; m < MF; m++) {
        const int row = wm + m * 16 + lr;
        af[m] = *(const bf16x8*)(sA + row * 64 + (((ks * 4 + kg) ^ swx) * 8));
      }
      #pragma unroll
      for (int n = 0; n < NF; n++) {
        const int row = wn + n * 16 + lr;
        bv[n] = *(const bf16x8*)(sB + row * 64 + (((ks * 4 + kg) ^ swx) * 8));
      }
      #pragma unroll
      for (int m = 0; m < MF; m++)
        #pragma unroll
        for (int n = 0; n < NF; n++)
          acc[m][n] = __builtin_amdgcn_mfma_f32_16x16x32_bf16(af[m], bv[n], acc[m][n], 0, 0, 0);
    }
  };

  if (nt > 0) {
    stage(0, kbeg);
    asm volatile("s_waitcnt vmcnt(0)" ::: "memory");
    __syncthreads();
    int cur = 0;
    for (int t = 0; t < nt; t++) {
      if (t + 1 < nt) stage(cur ^ 1, kbeg + (t + 1) * 64);
      compute(cur);
      asm volatile("s_waitcnt vmcnt(0)" ::: "memory");
      __syncthreads();
      cur ^= 1;
    }
  }

  if constexpr (EPI == 8) {
    if (bn >= 2560) {
      #pragma unroll
      for (int m = 0; m < MF; m++)
        #pragma unroll
        for (int n = 0; n < NF; n++)
          #pragma unroll
          for (int r = 0; r < 4; r++) {
            const int grow = bm + wm + m * 16 + kg * 4 + r;
            const int gcol = bn + wn + n * 16 + lr;
            vbo[(long)grow * 512 + (gcol - 2560)] = f2b(acc[m][n][r]);
          }
    } else {
      float* Cl = (float*)smem;  // [128][128] f32 = 64 KiB
      #pragma unroll
      for (int m = 0; m < MF; m++)
        #pragma unroll
        for (int n = 0; n < NF; n++)
          #pragma unroll
          for (int r = 0; r < 4; r++)
            Cl[(wm + m * 16 + kg * 4 + r) * 128 + wn + n * 16 + lr] = acc[m][n][r];
      __syncthreads();
      const int j = tid & 63;
      const int r2 = tid >> 6;
      #pragma unroll
      for (int it = 0; it < 16; it++) {
        const int row = r2 + it * 8;
        const int s = bm + row;
        const float c = rc[s * 64 + j], sn = rs[s * 64 + j];
        const float x1 = Cl[row * 128 + j], x2 = Cl[row * 128 + j + 64];
        const unsigned short o1 = f2b(x1 * c - x2 * sn);
        const unsigned short o2 = f2b(x2 * c + x1 * sn);
        if (bn < 2048) {
          unsigned short* qp = (unsigned short*)Cv + (long)s * 2048 + bn + j;
          qp[0] = o1; qp[64] = o2;
        } else {
          unsigned short* kp = kbo + (long)s * 512 + (bn - 2048) + j;
          kp[0] = o1; kp[64] = o2;
        }
      }
    }
    return;
  }

  #pragma unroll
  for (int m = 0; m < MF; m++) {
    #pragma unroll
    for (int n = 0; n < NF; n++) {
      #pragma unroll
      for (int r = 0; r < 4; r++) {
        const int grow = bm + wm + m * 16 + kg * 4 + r;
        const int gcol = bn + wn + n * 16 + lr;
        const long idx = (long)grow * ldc + gcol;
        float v = acc[m][n][r];
        if constexpr (EPI == 2) {
          ((unsigned short*)Cv)[idx] = f2b(v / (1.f + expf(-v)));
        } else if constexpr (EPI == 3) {
          ((float*)Cv)[idx] += v;
        } else if constexpr (EPI == 7) {
          ((float*)Cv)[(long)z * sCz + idx] = v;
        }
      }
    }
  }
}

// ---------------- 8-phase 256x256 GEMM, register read-ahead + XCD swizzle ----------------
template <int EPI>
__global__ __launch_bounds__(512, 1) void gemm8(
    const unsigned short* __restrict__ A0, const unsigned short* __restrict__ A1, int lda,
    const unsigned short* __restrict__ Bt, long sBz, int ldb,
    void* __restrict__ Cv, int ldc, long sCz, int K) {
  __shared__ __align__(16) unsigned short smem[2][4][8192];
  const int tid = threadIdx.x;
  const int lane = tid & 63;
  const int wave = tid >> 6;
  int bxi = blockIdx.x, byi = blockIdx.y, bzi = blockIdx.z;
  xcd_swizzle(bxi, byi, bzi);
  const int bm = byi * 256;
  const int bn = bxi * 256;
  const int z = bzi;
  const unsigned short* Aq;
  const unsigned short* Bq;
  if constexpr (EPI == 10) {
    Aq = z ? A1 : A0;
    Bq = Bt + (long)z * sBz;
  } else {
    Aq = A0 + z * 2048;
    Bq = Bt + z * 2048;
  }
  const int nt = K / 64;
  const int trow = tid >> 3;
  const int tc = tid & 7;
  const int sws = (tc ^ (trow & 7)) * 8;
  const int lr = lane & 15;
  const int kg = lane >> 4;
  const int wr = (wave >> 2) * 64;
  const int wc = (wave & 3) * 32;

  f32x4 acc[2][2][4][2];
  #pragma unroll
  for (int mh = 0; mh < 2; mh++)
    #pragma unroll
    for (int nh = 0; nh < 2; nh++)
      #pragma unroll
      for (int mf = 0; mf < 4; mf++)
        #pragma unroll
        for (int nf = 0; nf < 2; nf++) acc[mh][nh][mf][nf] = (f32x4){0.f, 0.f, 0.f, 0.f};

  bf16x8 af[2][4], af2[2][4], bv0[2][2], bv1[2][2];

  auto stageA = [&](int buf, int half, int k0) {
    const unsigned short* g = Aq + (long)(bm + half * 128 + trow) * lda + k0 + sws;
    unsigned short* l = &smem[buf][half][0] + tid * 8;
    gload16(g, l);
    gload16(g + (long)64 * lda, l + 4096);
  };
  auto stageB = [&](int buf, int half, int k0) {
    const unsigned short* g = Bq + (long)(bn + half * 128 + trow) * ldb + k0 + sws;
    unsigned short* l = &smem[buf][2 + half][0] + tid * 8;
    gload16(g, l);
    gload16(g + (long)64 * ldb, l + 4096);
  };

#define GSYNC(VM) \
  asm volatile("s_waitcnt vmcnt(" #VM ")" ::: "memory"); \
  __builtin_amdgcn_s_barrier(); \
  asm volatile("" ::: "memory"); \
  __builtin_amdgcn_sched_barrier(0)

#define RD_A(BUF, MH, DST) do { \
    _Pragma("unroll") \
    for (int ks = 0; ks < 2; ++ks) { \
      _Pragma("unroll") \
      for (int mf = 0; mf < 4; ++mf) { \
        const int row = wr + mf * 16 + lr; \
        DST[ks][mf] = *(const bf16x8*)(&smem[BUF][MH][0] + row * 64 + (((ks * 4 + kg) ^ (row & 7)) * 8)); \
      } \
    } \
  } while (0)

#define RD_B(BUF, NH, DST) do { \
    _Pragma("unroll") \
    for (int ks = 0; ks < 2; ++ks) { \
      _Pragma("unroll") \
      for (int nf = 0; nf < 2; ++nf) { \
        const int row = wc + nf * 16 + lr; \
        DST[ks][nf] = *(const bf16x8*)(&smem[BUF][2 + NH][0] + row * 64 + (((ks * 4 + kg) ^ (row & 7)) * 8)); \
      } \
    } \
  } while (0)

#define DO_MFMA(MH, NH, AF, BV) do { \
    __builtin_amdgcn_s_setprio(1); \
    _Pragma("unroll") \
    for (int ks = 0; ks < 2; ++ks) \
      _Pragma("unroll") \
      for (int mf = 0; mf < 4; ++mf) \
        _Pragma("unroll") \
        for (int nf = 0; nf < 2; ++nf) \
          acc[MH][NH][mf][nf] = __builtin_amdgcn_mfma_f32_16x16x32_bf16( \
              AF[ks][mf], BV[ks][nf], acc[MH][NH][mf][nf], 0, 0, 0); \
    __builtin_amdgcn_s_setprio(0); \
  } while (0)

  stageA(0, 0, 0); stageB(0, 0, 0); stageB(0, 1, 0); stageA(0, 1, 0);
  stageA(1, 0, 64); stageB(1, 1, 64); stageB(1, 0, 64);
  GSYNC(8);

  for (int t = 0; t <= nt - 3; ++t) {
    const int b = t & 1, nb = b ^ 1;
    const int k1 = (t + 1) << 6, k2 = (t + 2) << 6;
    RD_A(b, 0, af); RD_B(b, 0, bv0); RD_B(b, 1, bv1);
    stageA(nb, 1, k1); DO_MFMA(0, 0, af, bv0); GSYNC(8);
    RD_A(b, 1, af2);
    stageA(b, 0, k2); DO_MFMA(0, 1, af, bv1); GSYNC(8);
    stageB(b, 1, k2); DO_MFMA(1, 1, af2, bv1); GSYNC(8);
    RD_B(b, 0, bv0);
    stageB(b, 0, k2); DO_MFMA(1, 0, af2, bv0); GSYNC(8);
  }
  {
    const int t = nt - 2;
    const int b = t & 1, nb = b ^ 1;
    const int k1 = (t + 1) << 6;
    RD_A(b, 0, af); RD_B(b, 0, bv0); RD_B(b, 1, bv1);
    stageA(nb, 1, k1); DO_MFMA(0, 0, af, bv0); GSYNC(8);
    RD_A(b, 1, af2); DO_MFMA(0, 1, af, bv1); GSYNC(8);
    DO_MFMA(1, 1, af2, bv1); GSYNC(8);
    RD_B(b, 0, bv0); DO_MFMA(1, 0, af2, bv0); GSYNC(2);
  }
  {
    const int b = (nt - 1) & 1;
    RD_A(b, 0, af); RD_B(b, 0, bv0); RD_B(b, 1, bv1);
    DO_MFMA(0, 0, af, bv0); GSYNC(0);
    RD_A(b, 1, af2); DO_MFMA(0, 1, af, bv1);
    DO_MFMA(1, 1, af2, bv1);
    RD_B(b, 0, bv0); DO_MFMA(1, 0, af2, bv0);
  }
#undef DO_MFMA
#undef RD_B
#undef RD_A
#undef GSYNC

  #pragma unroll
  for (int mh = 0; mh < 2; mh++) {
    #pragma unroll
    for (int nh = 0; nh < 2; nh++) {
      #pragma unroll
      for (int mf = 0; mf < 4; mf++) {
        #pragma unroll
        for (int nf = 0; nf < 2; nf++) {
          #pragma unroll
          for (int r = 0; r < 4; r++) {
            const int grow = bm + mh * 128 + wr + mf * 16 + kg * 4 + r;
            const int gcol = bn + nh * 128 + wc + nf * 16 + lr;
            const long idx = (long)z * sCz + (long)grow * ldc + gcol;
            const float v = acc[mh][nh][mf][nf][r];
            if constexpr (EPI == 10) {
              ((unsigned short*)Cv)[idx] = f2b(v / (1.f + expf(-v)));
            } else {
              ((float*)Cv)[idx] = v;
            }
          }
        }
      }
    }
  }
}

__global__ __launch_bounds__(256) void fill_zero(float* p, long n) {
  const long i = (long)blockIdx.x * 256 + threadIdx.x;
  if (i < n) p[i] = 0.f;
}

extern "C" void kernel_launch(void* const* d_in, const int* in_sizes, int n_in,
                              void* d_out, int out_size, void* d_ws, size_t ws_size,
                              hipStream_t stream) {
  const int* ids = (const int*)d_in[0];
  const float* vocab_emb = (const float*)d_in[1];
  const float* audio_emb = (const float*)d_in[2];
  const float* ln_in_text = (const float*)d_in[3];
  const float* ln_in_audio = (const float*)d_in[4];
  const float* ln_post_text = (const float*)d_in[5];
  const float* ln_post_audio = (const float*)d_in[6];
  const float* wq = (const float*)d_in[7];
  const float* wk = (const float*)d_in[8];
  const float* wv = (const float*)d_in[9];
  const float* wo = (const float*)d_in[10];
  const float* wfc_t = (const float*)d_in[11];
  const float* wpj_t = (const float*)d_in[12];
  const float* wfc_a = (const float*)d_in[13];
  const float* wpj_a = (const float*)d_in[14];
  const float* ln_f = (const float*)d_in[15];

  size_t off = 0;
  auto alloc = [&](size_t bytes) -> void* {
    void* p = (char*)d_ws + off;
    off += (bytes + 255) & ~(size_t)255;
    return p;
  };
  const size_t LW = 77594624;
  unsigned short* wsT = (unsigned short*)alloc((size_t)2 * LW * 2);
  int* amask = (int*)alloc(S_LEN * 4);
  int* apos = (int*)alloc(S_LEN * 4);
  int* cnt = (int*)alloc(16);
  int* ctrs = (int*)alloc(16);
  float* ropec = (float*)alloc((size_t)S_LEN * 64 * 4);
  float* ropes = (float*)alloc((size_t)S_LEN * 64 * 4);
  float* h = (float*)alloc((size_t)S_LEN * HID * 4);
  unsigned short* hn = (unsigned short*)alloc((size_t)S_LEN * HID * 2);
  unsigned short* hnt = (unsigned short*)alloc((size_t)S_LEN * HID * 2);
  unsigned short* hna_g = (unsigned short*)alloc((size_t)S_LEN * HID * 2);
  unsigned short* qb = (unsigned short*)alloc((size_t)S_LEN * 2048 * 2);
  unsigned short* kb = (unsigned short*)alloc((size_t)S_LEN * 512 * 2);
  unsigned short* vb = (unsigned short*)alloc((size_t)S_LEN * 512 * 2);
  unsigned short* vt = (unsigned short*)alloc((size_t)512 * S_LEN * 2);
  unsigned short* o = (unsigned short*)alloc((size_t)S_LEN * 2048 * 2);
  float* stm = (float*)alloc((size_t)2 * 16 * 2048 * 4);
  float* stl = (float*)alloc((size_t)2 * 16 * 2048 * 4);
  char* big = (char*)alloc(268435456);
  float* opart = (float*)big;                      // [2][2048][2048] f32
  unsigned short* mlp_t = (unsigned short*)big;
  unsigned short* mlp_a = (unsigned short*)(big + 33554432);
  float* pt = (float*)(big + 67108864);
  float* pa = (float*)(big + 134217728);

  if (ws_size < off) {
    fill_zero<<<(out_size + 255) / 256, 256, 0, stream>>>((float*)d_out, out_size);
    return;
  }

  const size_t WO_ = 6291456, WFT = 10485760, WPT = 27262976, WFA = 44040192, WPA = 60817408;

  embed_kernel<<<S_LEN, 256, 0, stream>>>(ids, vocab_emb, audio_emb, h, amask);
  partition_rows<<<1, 256, 0, stream>>>(ids, apos, cnt);
  init_stats<<<256, 256, 0, stream>>>(stm, stl, ctrs);
  rope_table<<<S_LEN * 64 / 256, 256, 0, stream>>>(ropec, ropes);

  // batched weight transposes (z = layer)
  const long LWl = (long)LW;
  transposew<<<dim3(32, 32, 2), 256, 0, stream>>>(wq, 2048, wsT, 2048, 2048, 4194304, LWl);
  transposew<<<dim3(8, 32, 2), 256, 0, stream>>>(wk, 512, wsT + 4194304, 2048, 512, 1048576, LWl);
  transposew<<<dim3(8, 32, 2), 256, 0, stream>>>(wv, 512, wsT + 5242880, 2048, 512, 1048576, LWl);
  transposew<<<dim3(32, 32, 2), 256, 0, stream>>>(wo, 2048, wsT + WO_, 2048, 2048, 4194304, LWl);
  transposew<<<dim3(128, 32, 2), 256, 0, stream>>>(wfc_t, 8192, wsT + WFT, 2048, 8192, 16777216, LWl);
  transposew<<<dim3(32, 128, 2), 256, 0, stream>>>(wpj_t, 2048, wsT + WPT, 8192, 2048, 16777216, LWl);
  transposew<<<dim3(128, 32, 2), 256, 0, stream>>>(wfc_a, 8192, wsT + WFA, 2048, 8192, 16777216, LWl);
  transposew<<<dim3(32, 128, 2), 256, 0, stream>>>(wpj_a, 2048, wsT + WPA, 8192, 2048, 16777216, LWl);

  const float iscale = 0.08838834764831845f;  // 1/sqrt(128)
  for (int i = 0; i < 2; i++) {
    const size_t wb = (size_t)i * LW;
    rmsnorm_sel<<<S_LEN, 256, 0, stream>>>(h, amask, ln_in_text + i * HID, ln_in_audio + i * HID, hn);
    gemm2<128, 128, 8, 1><<<dim3(24, 16, 1), 512, 0, stream>>>(hn, 2048, 0, wsT + wb, 2048, 0,
        qb, 2048, 0, 0, 2048, 1.f, nullptr, 0, ropec, ropes, kb, vb);
    transpose_b16<<<dim3(8, 32), 256, 0, stream>>>(vb, vt);
    attn_flash<<<256, 512, 0, stream>>>(qb, kb, vt, opart, stm, stl, ctrs + i, iscale);
    o_merge2<<<16384, 256, 0, stream>>>(opart, stm, stl, o);
    gemm2<128, 128, 3, 1><<<dim3(16, 16, 1), 512, 0, stream>>>(o, 2048, 0, wsT + wb + WO_, 2048, 0,
        h, 2048, 0, 0, 2048, 1.f, nullptr, 0, nullptr, nullptr, nullptr, nullptr);
    rmsnorm_post<<<S_LEN, 256, 0, stream>>>(h, apos, ln_post_text + i * HID, ln_post_audio + i * HID, hnt, hna_g);
    gemm2<128, 128, 2, 0><<<dim3(64, 16, 1), 512, 0, stream>>>(hna_g, 2048, 0, wsT + wb + WFA, 2048, 0,
        mlp_a, 8192, 0, 0, 2048, 1.f, cnt, 0, nullptr, nullptr, nullptr, nullptr);
    gemm8<10><<<dim3(32, 8, 1), 512, 0, stream>>>(hnt, hnt, 2048, wsT + wb + WFT, 0, 2048,
        mlp_t, 8192, 0, 2048);
    gemm2<128, 128, 7, 0><<<dim3(16, 16, 8), 512, 0, stream>>>(mlp_a, 8192, 0, wsT + wb + WPA, 8192, 0,
        pa, 2048, (long)1 << 22, 0, 8192, 1.f, cnt, 1024, nullptr, nullptr, nullptr, nullptr);
    gemm8<11><<<dim3(8, 8, 4), 512, 0, stream>>>(mlp_t, mlp_t, 8192, wsT + wb + WPT, 0, 8192,
        pt, 2048, (long)1 << 22, 2048);
    mlp_reduce<<<16384, 256, 0, stream>>>(pt, pa, apos, h);
  }
  rmsnorm_final<<<S_LEN, 256, 0, stream>>>(h, ln_f, (float*)d_out);
}